// Round 9
// baseline (372.365 us; speedup 1.0000x reference)
//
#include <hip/hip_runtime.h>
#include <math.h>

#define BNUM 32
#define TT   512
#define DD   768
#define HH   12
#define DHH  64
#define RR   8
#define TSRC 256     // src (even) / dst (odd) token count
#define UNM  248     // unmerged src tokens
#define TM   504     // tokens after merge
#define MROW 16128   // BNUM * TM

typedef unsigned short u16;
typedef unsigned int   u32;
typedef __attribute__((ext_vector_type(8))) short bfrag;   // 8 bf16 = 4 VGPRs
typedef __attribute__((ext_vector_type(4))) float ffrag;   // 4 fp32 acc
typedef __attribute__((ext_vector_type(2))) unsigned int u32x2;

__device__ __forceinline__ u16 f2bf(float f) {
  u32 u = __float_as_uint(f);
  u = (u + 0x7fffu + ((u >> 16) & 1u)) >> 16;   // RNE
  return (u16)u;
}
// pack two floats as bf16 pair (RNE), b in high half
__device__ __forceinline__ u32 pack2bf(float a, float b) {
  u32 ua = __float_as_uint(a), ub = __float_as_uint(b);
  ua += 0x7fffu + ((ua >> 16) & 1u);
  ub += 0x7fffu + ((ub >> 16) & 1u);
  return (ua >> 16) | (ub & 0xffff0000u);
}
__device__ __forceinline__ float bf2f(u16 v) {
  return __uint_as_float(((u32)v) << 16);
}

// async global->LDS, 16B per lane: LDS dest = wave-uniform base + lane*16,
// global src = per-lane address (scatter-gather OK).
__device__ __forceinline__ void gl2lds16(const u16* g, u16* l) {
  __builtin_amdgcn_global_load_lds(
      (const __attribute__((address_space(1))) void*)(g),
      (__attribute__((address_space(3))) void*)(l), 16, 0, 0);
}

// ---------------------------------------------------------------------------
// Kernel 1: reduce Wk over heads -> Wkr (768x64), bkr (64)
__global__ __launch_bounds__(256) void wkr_kernel(
    const float* __restrict__ Wk, const float* __restrict__ bk,
    float* __restrict__ Wkr, float* __restrict__ bkr) {
  int idx = blockIdx.x * 256 + threadIdx.x;   // 0..49151
  int d = idx >> 6, j = idx & 63;
  float s = 0.f;
  #pragma unroll
  for (int h = 0; h < HH; ++h) s += Wk[(size_t)d * DD + h * DHH + j];
  Wkr[idx] = s * (1.f / 12.f);
  if (idx < 64) {
    float sb = 0.f;
    #pragma unroll
    for (int h = 0; h < HH; ++h) sb += bk[h * DHH + idx];
    bkr[idx] = sb * (1.f / 12.f);
  }
}

// ---------------------------------------------------------------------------
// fp32 GEMM for the decision-critical metric. BM=64, 4x4 tile per thread.
__global__ __launch_bounds__(256) void gemm_f32_kernel(
    const float* __restrict__ A, const float* __restrict__ W,
    const float* __restrict__ bias, float* __restrict__ C,
    int M, int N, int K) {
  __shared__ float As[32][68];   // [kk][m]: 272B rows (16B-aligned)
  __shared__ float Ws[32][68];   // [kk][n]
  const int t  = threadIdx.x;
  const int m0 = blockIdx.x * 64;
  const int tx = t & 15, ty = t >> 4;    // out: rows ty*4..+3, cols tx*4..+3
  const int a_kk = t & 31;
  const int a_m  = t >> 5;               // rows a_m + 8l, l=0..7
  const int w_n  = t & 63;
  const int w_k0 = t >> 6;               // kks w_k0*8 + l, l=0..7

  float a_pre[8], w_pre[8];
  #pragma unroll
  for (int l = 0; l < 8; ++l)
    a_pre[l] = A[(size_t)(m0 + a_m + 8 * l) * K + a_kk];
  #pragma unroll
  for (int l = 0; l < 8; ++l)
    w_pre[l] = W[(size_t)(w_k0 * 8 + l) * N + w_n];

  float acc[4][4];
  #pragma unroll
  for (int i = 0; i < 4; ++i)
    #pragma unroll
    for (int j = 0; j < 4; ++j) acc[i][j] = 0.f;

  for (int k0 = 0; k0 < K; k0 += 32) {
    __syncthreads();
    #pragma unroll
    for (int l = 0; l < 8; ++l) As[a_kk][a_m + 8 * l] = a_pre[l];
    #pragma unroll
    for (int l = 0; l < 8; ++l) Ws[w_k0 * 8 + l][w_n] = w_pre[l];
    __syncthreads();
    if (k0 + 32 < K) {   // prefetch next tile (hides latency behind compute)
      #pragma unroll
      for (int l = 0; l < 8; ++l)
        a_pre[l] = A[(size_t)(m0 + a_m + 8 * l) * K + k0 + 32 + a_kk];
      #pragma unroll
      for (int l = 0; l < 8; ++l)
        w_pre[l] = W[(size_t)(k0 + 32 + w_k0 * 8 + l) * N + w_n];
    }
    #pragma unroll
    for (int kk = 0; kk < 32; ++kk) {
      float4 a4 = *(const float4*)&As[kk][ty * 4];
      float4 w4 = *(const float4*)&Ws[kk][tx * 4];
      acc[0][0] += a4.x * w4.x; acc[0][1] += a4.x * w4.y;
      acc[0][2] += a4.x * w4.z; acc[0][3] += a4.x * w4.w;
      acc[1][0] += a4.y * w4.x; acc[1][1] += a4.y * w4.y;
      acc[1][2] += a4.y * w4.z; acc[1][3] += a4.y * w4.w;
      acc[2][0] += a4.z * w4.x; acc[2][1] += a4.z * w4.y;
      acc[2][2] += a4.z * w4.z; acc[2][3] += a4.z * w4.w;
      acc[3][0] += a4.w * w4.x; acc[3][1] += a4.w * w4.y;
      acc[3][2] += a4.w * w4.z; acc[3][3] += a4.w * w4.w;
    }
  }
  const float4 b4 = *(const float4*)&bias[tx * 4];
  #pragma unroll
  for (int i = 0; i < 4; ++i) {
    float4 v;
    v.x = acc[i][0] + b4.x; v.y = acc[i][1] + b4.y;
    v.z = acc[i][2] + b4.z; v.w = acc[i][3] + b4.w;
    *(float4*)&C[(size_t)(m0 + ty * 4 + i) * N + tx * 4] = v;
  }
}

// ---------------------------------------------------------------------------
// Weight convert+transpose: W (KxN fp32, K=N=768) -> WT (NxK bf16).
__global__ __launch_bounds__(256) void wconv_kernel(
    const float* __restrict__ W0, const float* __restrict__ W1,
    const float* __restrict__ W2, const float* __restrict__ W3,
    u16* __restrict__ T0, u16* __restrict__ T1,
    u16* __restrict__ T2, u16* __restrict__ T3) {
  __shared__ float tile[64][65];
  int wi = blockIdx.z;
  const float* W = (wi == 0) ? W0 : (wi == 1) ? W1 : (wi == 2) ? W2 : W3;
  u16* T = (wi == 0) ? T0 : (wi == 1) ? T1 : (wi == 2) ? T2 : T3;
  int k0 = blockIdx.x * 64, n0 = blockIdx.y * 64;
  int t = threadIdx.x;
  int r = t >> 2, c4 = (t & 3) * 16;
  #pragma unroll
  for (int j = 0; j < 16; j += 4) {
    float4 v = *(const float4*)&W[(size_t)(k0 + r) * DD + n0 + c4 + j];
    tile[r][c4 + j] = v.x; tile[r][c4 + j + 1] = v.y;
    tile[r][c4 + j + 2] = v.z; tile[r][c4 + j + 3] = v.w;
  }
  __syncthreads();
  #pragma unroll
  for (int j = 0; j < 16; j += 2) {
    u32 p = (u32)f2bf(tile[c4 + j][r]) | ((u32)f2bf(tile[c4 + j + 1][r]) << 16);
    *(u32*)&T[(size_t)(n0 + r) * DD + k0 + c4 + j] = p;
  }
}

// ---------------------------------------------------------------------------
// bf16 MFMA GEMM: C(MxN) = A(MxK bf16) @ BT(NxK bf16)^T + bias (+Res fp32)
// Double-buffered 2-phase schedule + bijective XCD swizzle + ASHARE decode
// order (round 8): ASHARE=1 n-fastest so each XCD chunk shares the A-band.
template <bool OUT_BF16, bool ADD_RES, bool ROW_BIAS, bool QK, bool ASHARE>
__global__ __launch_bounds__(256, 4) void mfma_gemm_kernel(
    const u16* __restrict__ A, const u16* __restrict__ BT,
    const float* __restrict__ bias, const float* __restrict__ bias2,
    const float* __restrict__ Res,
    float* __restrict__ Cf, u16* __restrict__ Cb, u16* __restrict__ Cb2,
    int M, int N, int K) {
  __shared__ u16 Als[2][128 * 32];
  __shared__ u16 Bls[2][128 * 32];
  const int t  = threadIdx.x;

  // bijective XCD-aware remap of the flattened block id (m204 formula)
  const int gx = gridDim.x, gy = gridDim.y;
  const int nwg = gx * gy;
  int id = blockIdx.x + blockIdx.y * gx;
  {
    const int qq = nwg >> 3, rr = nwg & 7;
    const int xcd = id & 7, pos = id >> 3;
    id = (xcd < rr) ? (xcd * (qq + 1) + pos)
                    : (rr * (qq + 1) + (xcd - rr) * qq + pos);
  }
  int bm, bn;
  if (ASHARE) { bm = id / gy; bn = id % gy; }   // n-fastest: ids share A-panel
  else        { bm = id % gx; bn = id / gx; }   // m-fastest: ids share B-panel
  const int m0 = bm * 128;
  const int n0 = bn * 128;

  const int lane = t & 63;
  const int w  = t >> 6;
  const int wm = w & 1, wn = w >> 1;
  const int q  = lane >> 4;
  const int lr = lane & 15;

  // staging lane constants (BK=32 swizzle, see round-4 derivation)
  const int srow = lane >> 2;                       // 0..15
  const int schk = (lane & 3) ^ ((lane >> 3) & 3);  // pre-swizzled source chunk
  const u16* gA = A  + (size_t)(m0 + w * 32 + srow) * K + schk * 8;
  const u16* gB = BT + (size_t)(n0 + w * 32 + srow) * K + schk * 8;

  // read-side effective chunk (lane-constant)
  const int ceff = q ^ ((lr >> 1) & 3);

  // QK routing (block-uniform)
  const float* biasp = bias;
  u16* Cbp = Cb;
  int n0c = n0;
  if (QK && n0 >= DD) { biasp = bias2; Cbp = Cb2; n0c = n0 - DD; }

  ffrag acc[4][4];
  #pragma unroll
  for (int i = 0; i < 4; ++i)
    #pragma unroll
    for (int j = 0; j < 4; ++j) {
      acc[i][j].x = 0.f; acc[i][j].y = 0.f; acc[i][j].z = 0.f; acc[i][j].w = 0.f;
    }

  auto STAGE = [&](int buf, int k0) {
    #pragma unroll
    for (int i = 0; i < 2; ++i) {
      gl2lds16(gA + (size_t)(i * 16) * K + k0, &Als[buf][(w * 32 + i * 16) * 32]);
      gl2lds16(gB + (size_t)(i * 16) * K + k0, &Bls[buf][(w * 32 + i * 16) * 32]);
    }
  };

  STAGE(0, 0);
  __syncthreads();

  const int NK = K >> 5;   // K/32
  for (int kt = 0; kt < NK; ++kt) {
    const int cur = kt & 1;
    if (kt + 1 < NK) STAGE(cur ^ 1, (kt + 1) << 5);

    bfrag af[4], bfv[4];
    #pragma unroll
    for (int mi = 0; mi < 4; ++mi)
      af[mi] = *(const bfrag*)&Als[cur][((wm * 4 + mi) * 64 + lr * 4 + ceff) * 8];
    #pragma unroll
    for (int ni = 0; ni < 4; ++ni)
      bfv[ni] = *(const bfrag*)&Bls[cur][((wn * 4 + ni) * 64 + lr * 4 + ceff) * 8];
    #pragma unroll
    for (int mi = 0; mi < 4; ++mi)
      #pragma unroll
      for (int ni = 0; ni < 4; ++ni)
        acc[mi][ni] = __builtin_amdgcn_mfma_f32_16x16x32_bf16(
            af[mi], bfv[ni], acc[mi][ni], 0, 0, 0);

    __syncthreads();   // prefetch of buf^1 landed; reads of buf done
  }

  float bcol[4];
  if (!ROW_BIAS) {
    #pragma unroll
    for (int ni = 0; ni < 4; ++ni)
      bcol[ni] = biasp[n0c + wn * 64 + ni * 16 + lr];
  }

  #pragma unroll
  for (int mi = 0; mi < 4; ++mi) {
    #pragma unroll
    for (int ni = 0; ni < 4; ++ni) {
      int gcol = n0c + wn * 64 + ni * 16 + lr;
      #pragma unroll
      for (int r = 0; r < 4; ++r) {
        int grow = m0 + wm * 64 + mi * 16 + q * 4 + r;
        size_t off = (size_t)grow * N + gcol;
        float v = acc[mi][ni][r];
        v += ROW_BIAS ? bias[grow] : bcol[ni];
        if (ADD_RES) v += Res[off];
        if (OUT_BF16) Cbp[off] = f2bf(v);
        else          Cf[off] = v;
      }
    }
  }
}

// ---------------------------------------------------------------------------
// Kernel 3a: per-(batch, 32-row-group) scores max/argmax (exact).
__global__ __launch_bounds__(256) void tome_scores_kernel(
    const float* __restrict__ metric, float* __restrict__ node_max,
    int* __restrict__ node_idx) {
  __shared__ float Bs[128][68];
  const int blk = blockIdx.x;
  const int b = blk >> 3, g = blk & 7;
  const int t = threadIdx.x;
  const int r = t >> 3, cc = t & 7;
  const int arow = g * 32 + r;
  const float* Mb = metric + (size_t)b * TT * 64;

  float areg[64];
  float na = 0.f;
  #pragma unroll
  for (int d4 = 0; d4 < 16; ++d4) {
    float4 v = *(const float4*)&Mb[(size_t)(2 * arow) * 64 + d4 * 4];
    areg[4 * d4 + 0] = v.x; areg[4 * d4 + 1] = v.y;
    areg[4 * d4 + 2] = v.z; areg[4 * d4 + 3] = v.w;
    na += v.x * v.x; na += v.y * v.y; na += v.z * v.z; na += v.w * v.w;
  }
  float ia = 1.f / (sqrtf(na) + 1e-6f);
  #pragma unroll
  for (int d = 0; d < 64; ++d) areg[d] *= ia;

  float best = -INFINITY; int besti = 0;
  for (int p = 0; p < 2; ++p) {
    __syncthreads();            // prior pass reads done
    if (t < 128) {              // stage cols p*128 .. +127, normalized
      int c = p * 128 + t;
      const float* src = &Mb[(size_t)(2 * c + 1) * 64];
      float nb = 0.f;
      #pragma unroll
      for (int d4 = 0; d4 < 16; ++d4) {
        float4 v = *(const float4*)&src[d4 * 4];
        *(float4*)&Bs[t][d4 * 4] = v;
        nb += v.x * v.x; nb += v.y * v.y; nb += v.z * v.z; nb += v.w * v.w;
      }
      float ib = 1.f / (sqrtf(nb) + 1e-6f);
      #pragma unroll
      for (int d4 = 0; d4 < 16; ++d4) {
        float4 v = *(float4*)&Bs[t][d4 * 4];
        v.x *= ib; v.y *= ib; v.z *= ib; v.w *= ib;
        *(float4*)&Bs[t][d4 * 4] = v;
      }
    }
    __syncthreads();
    for (int j = 0; j < 16; ++j) {
      int cl = cc + 8 * j;
      float s = 0.f;
      #pragma unroll
      for (int d4 = 0; d4 < 16; ++d4) {
        float4 bv = *(const float4*)&Bs[cl][d4 * 4];
        s += areg[4 * d4 + 0] * bv.x; s += areg[4 * d4 + 1] * bv.y;
        s += areg[4 * d4 + 2] * bv.z; s += areg[4 * d4 + 3] * bv.w;
      }
      int c = p * 128 + cl;
      if (s > best) { best = s; besti = c; }
    }
  }
  #pragma unroll
  for (int off = 1; off < 8; off <<= 1) {
    float bm = __shfl_xor(best, off);
    int   bi = __shfl_xor(besti, off);
    if (bm > best || (bm == best && bi < besti)) { best = bm; besti = bi; }
  }
  if (cc == 0) {
    node_max[b * TSRC + arow] = best;
    node_idx[b * TSRC + arow] = besti;
  }
}

// ---------------------------------------------------------------------------
// Kernel 3b: per-batch ranking + top-R selection (exact).
__global__ __launch_bounds__(256) void tome_rank_kernel(
    const float* __restrict__ node_max, const int* __restrict__ node_idx,
    int* __restrict__ order_g, int* __restrict__ dst_g) {
  __shared__ float km[TSRC];
  __shared__ int ord[TSRC];
  int b = blockIdx.x, i = threadIdx.x;
  float best = (i == 0) ? -INFINITY : node_max[b * TSRC + i];
  km[i] = best;
  __syncthreads();
  float ki = km[i];
  int r = 0;
  for (int j = 0; j < TSRC; ++j) {
    float kj = km[j];
    if (kj > ki || (kj == ki && j < i)) ++r;
  }
  ord[r] = i;
  __syncthreads();
  order_g[b * TSRC + i] = ord[i];
  if (i < RR) dst_g[b * RR + i] = node_idx[b * TSRC + ord[i]];
}

// ---------------------------------------------------------------------------
// Kernel 4: merge X -> Xm (fp32 residual) + Xm_bf (bf16 GEMM operand).
__global__ __launch_bounds__(256) void merge_kernel(
    const float* __restrict__ X, const int* __restrict__ order,
    const int* __restrict__ dsti, float* __restrict__ Xm,
    u16* __restrict__ Xmb) {
  int row = blockIdx.x;
  int b = row / TM, t2 = row % TM;
  int c = threadIdx.x;
  const float* Xb = X + (size_t)b * TT * DD;
  float out[3];
  if (t2 < UNM) {
    int tok = 2 * order[b * TSRC + RR + t2];
    #pragma unroll
    for (int l = 0; l < 3; ++l) out[l] = Xb[(size_t)tok * DD + c + 256 * l];
  } else {
    int j = t2 - UNM;
    float cnt = 1.f;
    #pragma unroll
    for (int l = 0; l < 3; ++l) out[l] = Xb[(size_t)(2 * j + 1) * DD + c + 256 * l];
    for (int m = 0; m < RR; ++m) {
      if (dsti[b * RR + m] == j) {
        int tok = 2 * order[b * TSRC + m];
        #pragma unroll
        for (int l = 0; l < 3; ++l) out[l] += Xb[(size_t)tok * DD + c + 256 * l];
        cnt += 1.f;
      }
    }
    float inv = 1.f / cnt;
    #pragma unroll
    for (int l = 0; l < 3; ++l) out[l] *= inv;
  }
  #pragma unroll
  for (int l = 0; l < 3; ++l) {
    Xm[(size_t)row * DD + c + 256 * l]  = out[l];
    Xmb[(size_t)row * DD + c + 256 * l] = f2bf(out[l]);
  }
}

// ---------------------------------------------------------------------------
// Kernel 5: MFMA flash attention, P never leaves registers (round 6).
// Round-9 fixes:
//  (1) launch_bounds (256,5) -> (256,4): round-8's compile emitted 44 VGPRs
//      (below the ~70-reg live set) -> serialized scheduling, 86us. 128-reg
//      budget frees the allocator; HW occupancy still 5 blocks/CU (LDS cap)
//      if the emitted count stays <= ~102.
//  (2) V-tile swizzle gains a row-half term: slot s of row r holds global
//      chunk s ^ (r&7) ^ (((r>>3)&1)<<2). Staging: second V gl2lds16
//      sources schk^4. Reads: XOR hx=(lr>>3)<<2. This makes the PV
//      ds_read_b64 banks exactly 2/bank per 32-lane phase (the floor);
//      round-8's layout had lr and lr+8 on identical bank pairs (2-way
//      beyond floor -> 6.29M conflict cycles).
#define NQT 8
__global__ __launch_bounds__(256, 4) void attn_kernel(
    const u16* __restrict__ Q, const u16* __restrict__ K,
    const u16* __restrict__ VT, u16* __restrict__ ctx) {
  __shared__ u16 Kls[2][64][64];   // [buf][token][dim], chunk-swizzled
  __shared__ u16 Vls[2][64][64];   // [buf][dim][token], chunk+rowhalf-swizzled

  int blk = blockIdx.x;
  int bh = blk % (BNUM * HH);
  int qt = blk / (BNUM * HH);
  int h = bh % HH, b = bh / HH;
  const int t = threadIdx.x;
  const int lane = t & 63, w = t >> 6;
  const int lr = lane & 15, quad = lane >> 4;
  const int q0 = qt * 64;
  const size_t base = (size_t)b * TM * DD + (size_t)h * DHH;

  // Preload Q B-fragments: col n = lr -> q-row q0+16w+lr
  bfrag qf[2];
  {
    const u16* qp = Q + base + (size_t)(q0 + 16 * w + lr) * DD + quad * 8;
    qf[0] = *(const bfrag*)(qp);
    qf[1] = *(const bfrag*)(qp + 32);
  }

  // staging lane constants (see round-2 comment)
  const int srow = lane >> 3;
  const int schk = (lane & 7) ^ srow;
  const u16* Kg = K + base + (size_t)schk * 8;
  const u16* Vg0 = VT + (size_t)(h * DHH + w * 16 + srow) * MROW + (size_t)b * TM;
  const u16* Vg1 = Vg0 + (size_t)8 * MROW;

  // fragment-read chunk indices (swizzle involution on the read side)
  const int cA = (quad)     ^ (lr & 7);
  const int cB = (quad + 4) ^ (lr & 7);
  // PV b64 read offsets: logical chunk for token m*16+quad*4 is 2m+(quad>>1);
  // physical = logical ^ (lr&7) ^ hx; within-chunk byte offset (quad&1)*4.
  const int vq = quad >> 1, vh = (quad & 1) * 4, lx = lr & 7;
  const int hx = (lr >> 3) << 2;

  float m_i = -INFINITY, l_i = 0.f;   // running max in SCALED domain
  ffrag o[4];
  #pragma unroll
  for (int ni = 0; ni < 4; ++ni) {
    o[ni].x = 0.f; o[ni].y = 0.f; o[ni].z = 0.f; o[ni].w = 0.f;
  }

  auto STAGE = [&](int cur, int kt) {
    const int k0s = kt * 64;
    int t0 = k0s + w * 16 + srow;
    int t1 = t0 + 8;
    t0 = (t0 < TM) ? t0 : (TM - 1);
    t1 = (t1 < TM) ? t1 : (TM - 1);
    gl2lds16(Kg + (size_t)t0 * DD, &Kls[cur][w * 16][0]);
    gl2lds16(Kg + (size_t)t1 * DD, &Kls[cur][w * 16 + 8][0]);
    // V rows w*16..+7: rowhalf bit 0 -> source chunk schk
    int tb = k0s + schk * 8;
    tb = (tb <= TM - 8) ? tb : (TM - 8);
    gl2lds16(Vg0 + tb, &Vls[cur][w * 16][0]);
    // V rows w*16+8..+15: rowhalf bit 1 -> source chunk schk^4
    int tb2 = k0s + (schk ^ 4) * 8;
    tb2 = (tb2 <= TM - 8) ? tb2 : (TM - 8);
    gl2lds16(Vg1 + tb2, &Vls[cur][w * 16 + 8][0]);
  };

  STAGE(0, 0);
  __syncthreads();

  const float L2E = 1.4426950408889634f;
  const float C1  = 0.125f * 1.4426950408889634f;

  #pragma unroll
  for (int kt = 0; kt < NQT; ++kt) {
    const int cur = kt & 1;

    // issue next tile's staging first: latency hides under this tile's
    // compute; barrier at iteration end drains it.
    if (kt + 1 < NQT) STAGE(cur ^ 1, kt + 1);

    // S^T tile from LDS: s4[mi] covers tokens kt*64+mi*16+quad*4+r, row lr
    ffrag s4[4];
    __builtin_amdgcn_s_setprio(1);
    #pragma unroll
    for (int mi = 0; mi < 4; ++mi) {
      bfrag ka0 = *(const bfrag*)&Kls[cur][mi * 16 + lr][cA * 8];
      bfrag ka1 = *(const bfrag*)&Kls[cur][mi * 16 + lr][cB * 8];
      ffrag z; z.x = 0.f; z.y = 0.f; z.z = 0.f; z.w = 0.f;
      z = __builtin_amdgcn_mfma_f32_16x16x32_bf16(ka0, qf[0], z, 0, 0, 0);
      s4[mi] = __builtin_amdgcn_mfma_f32_16x16x32_bf16(ka1, qf[1], z, 0, 0, 0);
    }
    __builtin_amdgcn_s_setprio(0);

    // mask only the last tile (tokens 448..511 vs TM=504)
    if (kt == NQT - 1) {
      #pragma unroll
      for (int mi = 0; mi < 4; ++mi)
        #pragma unroll
        for (int r = 0; r < 4; ++r) {
          int rel = mi * 16 + quad * 4 + r;
          if (mi == 3)   // only mi==3 can overflow (rel>=56)
            s4[mi][r] = (448 + rel < TM) ? s4[mi][r] : -INFINITY;
        }
    }

    // raw-domain max, tree reduce (x0.125 is exact pow-2 scaling)
    float mx01 = fmaxf(fmaxf(s4[0][0], s4[0][1]), fmaxf(s4[0][2], s4[0][3]));
    float mx23 = fmaxf(fmaxf(s4[1][0], s4[1][1]), fmaxf(s4[1][2], s4[1][3]));
    float mx45 = fmaxf(fmaxf(s4[2][0], s4[2][1]), fmaxf(s4[2][2], s4[2][3]));
    float mx67 = fmaxf(fmaxf(s4[3][0], s4[3][1]), fmaxf(s4[3][2], s4[3][3]));
    float rmax = fmaxf(fmaxf(mx01, mx23), fmaxf(mx45, mx67));
    rmax = fmaxf(rmax, __shfl_xor(rmax, 16));
    rmax = fmaxf(rmax, __shfl_xor(rmax, 32));
    float pmax = rmax * 0.125f;

    // T13 defer-max: rescale only if some q-row's max grew by >8.
    if (!__all(pmax <= m_i + 8.f)) {
      float nm = fmaxf(m_i, pmax);
      float alpha = __builtin_amdgcn_exp2f((m_i - nm) * L2E);  // first: 0
      float al[4];
      #pragma unroll
      for (int r = 0; r < 4; ++r) al[r] = __shfl(alpha, quad * 4 + r);
      #pragma unroll
      for (int ni = 0; ni < 4; ++ni)
        #pragma unroll
        for (int r = 0; r < 4; ++r) o[ni][r] *= al[r];
      l_i *= alpha;
      m_i = nm;
    }
    float nml2 = m_i * L2E;

    // p = exp2(s*0.125*log2e - m*log2e) == exp(s*0.125 - m), bounded e^8
    float p[16];
    float pa0 = 0.f, pa1 = 0.f, pa2 = 0.f, pa3 = 0.f;
    #pragma unroll
    for (int mi = 0; mi < 4; ++mi)
      #pragma unroll
      for (int r = 0; r < 4; ++r) {
        float e = __builtin_amdgcn_exp2f(__builtin_fmaf(s4[mi][r], C1, -nml2));
        p[mi * 4 + r] = e;
        if (r == 0) pa0 += e; else if (r == 1) pa1 += e;
        else if (r == 2) pa2 += e; else pa3 += e;
      }
    float psum = (pa0 + pa1) + (pa2 + pa3);
    psum += __shfl_xor(psum, 16);
    psum += __shfl_xor(psum, 32);
    l_i += psum;

    // pack P in-register: pk[2mi] = tokens mi*16+quad*4+{0,1},
    // pk[2mi+1] = +{2,3} (bf16 pairs)
    u32 pk[8];
    #pragma unroll
    for (int mi = 0; mi < 4; ++mi) {
      pk[2 * mi]     = pack2bf(p[mi * 4 + 0], p[mi * 4 + 1]);
      pk[2 * mi + 1] = pack2bf(p[mi * 4 + 2], p[mi * 4 + 3]);
    }

    // PV: A = pk (registers, relabeled k-slots), B = V tokens from LDS
    __builtin_amdgcn_s_setprio(1);
    #pragma unroll
    for (int mh = 0; mh < 2; ++mh) {
      // A-frag: shorts 0..3 = tokens (2mh)*16+quad*4..+3,
      //         shorts 4..7 = tokens (2mh+1)*16+quad*4..+3
      union { u32 u[4]; bfrag f; } pa;
      pa.u[0] = pk[4 * mh + 0]; pa.u[1] = pk[4 * mh + 1];
      pa.u[2] = pk[4 * mh + 2]; pa.u[3] = pk[4 * mh + 3];
      const int c0 = ((4 * mh + vq) ^ lx ^ hx) * 8 + vh;       // m = 2mh
      const int c1 = ((4 * mh + 2 + vq) ^ lx ^ hx) * 8 + vh;   // m = 2mh+1
      #pragma unroll
      for (int ni = 0; ni < 4; ++ni) {
        const u16* vp = &Vls[cur][ni * 16 + lr][0];
        u32x2 v0 = *(const u32x2*)(vp + c0);
        u32x2 v1 = *(const u32x2*)(vp + c1);
        union { u32 u[4]; bfrag f; } vb;
        vb.u[0] = v0.x; vb.u[1] = v0.y; vb.u[2] = v1.x; vb.u[3] = v1.y;
        o[ni] = __builtin_amdgcn_mfma_f32_16x16x32_bf16(pa.f, vb.f, o[ni], 0, 0, 0);
      }
    }
    __builtin_amdgcn_s_setprio(0);

    __syncthreads();   // staged tile kt+1 complete; buf reuse safe
  }

  // epilogue: O /= l, store bf16
  float invl[4];
  #pragma unroll
  for (int r = 0; r < 4; ++r) {
    float lv = __shfl(l_i, quad * 4 + r);
    invl[r] = 1.f / lv;
  }
  #pragma unroll
  for (int r = 0; r < 4; ++r) {
    int row = q0 + 16 * w + quad * 4 + r;
    if (row < TM) {
      size_t g = base + (size_t)row * DD + lr;
      #pragma unroll
      for (int ni = 0; ni < 4; ++ni)
        ctx[g + ni * 16] = f2bf(o[ni][r] * invl[r]);
    }
  }
}

// ---------------------------------------------------------------------------
// Kernel 7: in-place LayerNorm on d_out rows (768 wide).
__global__ __launch_bounds__(256) void ln_kernel(
    float* __restrict__ Y, const float* __restrict__ g,
    const float* __restrict__ beta) {
  __shared__ float red[4];
  int row = blockIdx.x, t = threadIdx.x;
  size_t baseo = (size_t)row * DD;
  float x[3];
  #pragma unroll
  for (int l = 0; l < 3; ++l) x[l] = Y[baseo + t + 256 * l];
  float s = x[0] + x[1] + x[2];
  #pragma unroll
  for (int off = 32; off > 0; off >>= 1) s += __shfl_down(s, off, 64);
  if ((t & 63) == 0) red[t >> 6] = s;
  __syncthreads();
  float mu = (red[0] + red[1] + red[2] + red[3]) * (1.f / 768.f);
  __syncthreads();
  float d0 = x[0] - mu, d1 = x[1] - mu, d2 = x[2] - mu;
  float sq = d0 * d0 + d1 * d1 + d2 * d2;
  #pragma unroll
  for (int off = 32; off > 0; off >>= 1) sq += __shfl_down(sq, off, 64);
  if ((t & 63) == 0) red[t >> 6] = sq;
  __syncthreads();
  float var = (red[0] + red[1] + red[2] + red[3]) * (1.f / 768.f);
  float inv = rsqrtf(var + 1e-12f);
  #pragma unroll
  for (int l = 0; l < 3; ++l) {
    int c = t + 256 * l;
    Y[baseo + c] = (x[l] - mu) * inv * g[c] + beta[c];
  }
}

// ---------------------------------------------------------------------------
extern "C" void kernel_launch(void* const* d_in, const int* in_sizes, int n_in,
                              void* d_out, int out_size, void* d_ws, size_t ws_size,
                              hipStream_t stream) {
  const float* X    = (const float*)d_in[0];
  const float* Wq   = (const float*)d_in[1];
  const float* bq   = (const float*)d_in[2];
  const float* Wk   = (const float*)d_in[3];
  const float* bk   = (const float*)d_in[4];
  const float* Wv   = (const float*)d_in[5];
  const float* bv   = (const float*)d_in[6];
  const float* Wo   = (const float*)d_in[7];
  const float* bo   = (const float*)d_in[8];
  const float* ln_g = (const float*)d_in[9];
  const float* ln_b = (const float*)d_in[10];
  float* out = (float*)d_out;

  const size_t metric_n = (size_t)16384 * 64;
  const size_t wkr_n    = (size_t)768 * 64 + 64;
  const size_t idx_n    = (size_t)BNUM * TSRC + BNUM * RR;
  const size_t nm_n     = (size_t)2 * BNUM * TSRC;   // node_max f32 + node_idx int
  const size_t buf_n    = (size_t)MROW * DD;
  const size_t w_n      = (size_t)DD * DD;
  const size_t f32_elems = metric_n + wkr_n + idx_n + nm_n + buf_n;
  const size_t u16_elems = 4 * buf_n + 4 * w_n;
  const size_t needed = f32_elems * 4 + u16_elems * 2;
  if (ws_size < needed) return;

  float* ws = (float*)d_ws;
  float* metric   = ws;
  float* Wkr      = metric + metric_n;
  float* bkr      = Wkr + (size_t)768 * 64;
  int*   order_g  = (int*)(bkr + 64);
  int*   dst_g    = order_g + BNUM * TSRC;
  float* node_max = (float*)(dst_g + BNUM * RR);
  int*   node_idx = (int*)(node_max + BNUM * TSRC);
  float* Xm       = (float*)(node_idx + BNUM * TSRC);
  u16*   Xmb      = (u16*)(Xm + buf_n);
  u16*   Qmb      = Xmb + buf_n;
  u16*   Kmb      = Qmb + buf_n;
  u16*   VTb      = Kmb + buf_n;     // V^T: [768][MROW]
  u16*   WqT      = VTb + buf_n;
  u16*   WkT      = WqT + w_n;       // contiguous after WqT -> [1536][768]
  u16*   WvT      = WkT + w_n;
  u16*   WoT      = WvT + w_n;
  u16*   ctxb     = Qmb;   // alias: safe, see attn_kernel note

  wkr_kernel<<<(768 * 64) / 256, 256, 0, stream>>>(Wk, bk, Wkr, bkr);
  wconv_kernel<<<dim3(12, 12, 4), 256, 0, stream>>>(
      Wq, Wk, Wv, Wo, WqT, WkT, WvT, WoT);
  gemm_f32_kernel<<<dim3(16384 / 64, 1), 256, 0, stream>>>(
      X, Wkr, bkr, metric, 16384, 64, 768);
  tome_scores_kernel<<<BNUM * 8, 256, 0, stream>>>(metric, node_max, node_idx);
  tome_rank_kernel<<<BNUM, 256, 0, stream>>>(node_max, node_idx, order_g, dst_g);
  merge_kernel<<<MROW, 256, 0, stream>>>(X, order_g, dst_g, Xm, Xmb);
  // Q and K fused: B = [WqT|WkT]; ASHARE=1 (A=Xmb is the big re-read operand)
  mfma_gemm_kernel<true, false, false, true, true>
      <<<dim3(MROW / 128, 2 * DD / 128), 256, 0, stream>>>(
      Xmb, WqT, bq, bk, nullptr, nullptr, Qmb, Kmb, MROW, DD, DD);
  // V^T: A = WvT (tiny), B = Xmb (big) -> keep m-fastest (ASHARE=0)
  mfma_gemm_kernel<true, false, true, false, false>
      <<<dim3(DD / 128, MROW / 128), 256, 0, stream>>>(
      WvT, Xmb, bv, nullptr, nullptr, nullptr, VTb, nullptr, DD, MROW, DD);
  attn_kernel<<<BNUM * HH * NQT, 256, 0, stream>>>(Qmb, Kmb, VTb, ctxb);
  // Wo: A = ctx (big re-read) -> ASHARE=1
  mfma_gemm_kernel<false, true, false, false, true>
      <<<dim3(MROW / 128, DD / 128), 256, 0, stream>>>(
      ctxb, WoT, bo, nullptr, Xm, out, nullptr, nullptr, MROW, DD, DD);
  ln_kernel<<<MROW, 256, 0, stream>>>(out, ln_g, ln_b);
}

// Round 10
// 367.645 us; speedup vs baseline: 1.0128x; 1.0128x over previous
//
#include <hip/hip_runtime.h>
#include <math.h>

#define BNUM 32
#define TT   512
#define DD   768
#define HH   12
#define DHH  64
#define RR   8
#define TSRC 256     // src (even) / dst (odd) token count
#define UNM  248     // unmerged src tokens
#define TM   504     // tokens after merge
#define MROW 16128   // BNUM * TM

typedef unsigned short u16;
typedef unsigned int   u32;
typedef __attribute__((ext_vector_type(8))) short bfrag;   // 8 bf16 = 4 VGPRs
typedef __attribute__((ext_vector_type(4))) float ffrag;   // 4 fp32 acc
typedef __attribute__((ext_vector_type(2))) unsigned int u32x2;

__device__ __forceinline__ u16 f2bf(float f) {
  u32 u = __float_as_uint(f);
  u = (u + 0x7fffu + ((u >> 16) & 1u)) >> 16;   // RNE
  return (u16)u;
}
// HW packed f32->bf16 (RNE, same rounding as f2bf): 1 VALU instr vs ~5.
__device__ __forceinline__ u32 cvtpk2bf(float a, float b) {
  u32 r;
  asm("v_cvt_pk_bf16_f32 %0, %1, %2" : "=v"(r) : "v"(a), "v"(b));
  return r;
}
__device__ __forceinline__ float bf2f(u16 v) {
  return __uint_as_float(((u32)v) << 16);
}
__device__ __forceinline__ float max3f(float a, float b, float c) {
  return fmaxf(fmaxf(a, b), c);   // clang fuses to v_max3_f32
}

// async global->LDS, 16B per lane: LDS dest = wave-uniform base + lane*16,
// global src = per-lane address (scatter-gather OK).
__device__ __forceinline__ void gl2lds16(const u16* g, u16* l) {
  __builtin_amdgcn_global_load_lds(
      (const __attribute__((address_space(1))) void*)(g),
      (__attribute__((address_space(3))) void*)(l), 16, 0, 0);
}

// ---------------------------------------------------------------------------
// Kernel 1: reduce Wk over heads -> Wkr (768x64), bkr (64)
__global__ __launch_bounds__(256) void wkr_kernel(
    const float* __restrict__ Wk, const float* __restrict__ bk,
    float* __restrict__ Wkr, float* __restrict__ bkr) {
  int idx = blockIdx.x * 256 + threadIdx.x;   // 0..49151
  int d = idx >> 6, j = idx & 63;
  float s = 0.f;
  #pragma unroll
  for (int h = 0; h < HH; ++h) s += Wk[(size_t)d * DD + h * DHH + j];
  Wkr[idx] = s * (1.f / 12.f);
  if (idx < 64) {
    float sb = 0.f;
    #pragma unroll
    for (int h = 0; h < HH; ++h) sb += bk[h * DHH + idx];
    bkr[idx] = sb * (1.f / 12.f);
  }
}

// ---------------------------------------------------------------------------
// fp32 GEMM for the decision-critical metric. BM=64, 4x4 tile per thread.
__global__ __launch_bounds__(256) void gemm_f32_kernel(
    const float* __restrict__ A, const float* __restrict__ W,
    const float* __restrict__ bias, float* __restrict__ C,
    int M, int N, int K) {
  __shared__ float As[32][68];   // [kk][m]: 272B rows (16B-aligned)
  __shared__ float Ws[32][68];   // [kk][n]
  const int t  = threadIdx.x;
  const int m0 = blockIdx.x * 64;
  const int tx = t & 15, ty = t >> 4;    // out: rows ty*4..+3, cols tx*4..+3
  const int a_kk = t & 31;
  const int a_m  = t >> 5;               // rows a_m + 8l, l=0..7
  const int w_n  = t & 63;
  const int w_k0 = t >> 6;               // kks w_k0*8 + l, l=0..7

  float a_pre[8], w_pre[8];
  #pragma unroll
  for (int l = 0; l < 8; ++l)
    a_pre[l] = A[(size_t)(m0 + a_m + 8 * l) * K + a_kk];
  #pragma unroll
  for (int l = 0; l < 8; ++l)
    w_pre[l] = W[(size_t)(w_k0 * 8 + l) * N + w_n];

  float acc[4][4];
  #pragma unroll
  for (int i = 0; i < 4; ++i)
    #pragma unroll
    for (int j = 0; j < 4; ++j) acc[i][j] = 0.f;

  for (int k0 = 0; k0 < K; k0 += 32) {
    __syncthreads();
    #pragma unroll
    for (int l = 0; l < 8; ++l) As[a_kk][a_m + 8 * l] = a_pre[l];
    #pragma unroll
    for (int l = 0; l < 8; ++l) Ws[w_k0 * 8 + l][w_n] = w_pre[l];
    __syncthreads();
    if (k0 + 32 < K) {   // prefetch next tile (hides latency behind compute)
      #pragma unroll
      for (int l = 0; l < 8; ++l)
        a_pre[l] = A[(size_t)(m0 + a_m + 8 * l) * K + k0 + 32 + a_kk];
      #pragma unroll
      for (int l = 0; l < 8; ++l)
        w_pre[l] = W[(size_t)(k0 + 32 + w_k0 * 8 + l) * N + w_n];
    }
    #pragma unroll
    for (int kk = 0; kk < 32; ++kk) {
      float4 a4 = *(const float4*)&As[kk][ty * 4];
      float4 w4 = *(const float4*)&Ws[kk][tx * 4];
      acc[0][0] += a4.x * w4.x; acc[0][1] += a4.x * w4.y;
      acc[0][2] += a4.x * w4.z; acc[0][3] += a4.x * w4.w;
      acc[1][0] += a4.y * w4.x; acc[1][1] += a4.y * w4.y;
      acc[1][2] += a4.y * w4.z; acc[1][3] += a4.y * w4.w;
      acc[2][0] += a4.z * w4.x; acc[2][1] += a4.z * w4.y;
      acc[2][2] += a4.z * w4.z; acc[2][3] += a4.z * w4.w;
      acc[3][0] += a4.w * w4.x; acc[3][1] += a4.w * w4.y;
      acc[3][2] += a4.w * w4.z; acc[3][3] += a4.w * w4.w;
    }
  }
  const float4 b4 = *(const float4*)&bias[tx * 4];
  #pragma unroll
  for (int i = 0; i < 4; ++i) {
    float4 v;
    v.x = acc[i][0] + b4.x; v.y = acc[i][1] + b4.y;
    v.z = acc[i][2] + b4.z; v.w = acc[i][3] + b4.w;
    *(float4*)&C[(size_t)(m0 + ty * 4 + i) * N + tx * 4] = v;
  }
}

// ---------------------------------------------------------------------------
// Weight convert+transpose: W (KxN fp32, K=N=768) -> WT (NxK bf16).
__global__ __launch_bounds__(256) void wconv_kernel(
    const float* __restrict__ W0, const float* __restrict__ W1,
    const float* __restrict__ W2, const float* __restrict__ W3,
    u16* __restrict__ T0, u16* __restrict__ T1,
    u16* __restrict__ T2, u16* __restrict__ T3) {
  __shared__ float tile[64][65];
  int wi = blockIdx.z;
  const float* W = (wi == 0) ? W0 : (wi == 1) ? W1 : (wi == 2) ? W2 : W3;
  u16* T = (wi == 0) ? T0 : (wi == 1) ? T1 : (wi == 2) ? T2 : T3;
  int k0 = blockIdx.x * 64, n0 = blockIdx.y * 64;
  int t = threadIdx.x;
  int r = t >> 2, c4 = (t & 3) * 16;
  #pragma unroll
  for (int j = 0; j < 16; j += 4) {
    float4 v = *(const float4*)&W[(size_t)(k0 + r) * DD + n0 + c4 + j];
    tile[r][c4 + j] = v.x; tile[r][c4 + j + 1] = v.y;
    tile[r][c4 + j + 2] = v.z; tile[r][c4 + j + 3] = v.w;
  }
  __syncthreads();
  #pragma unroll
  for (int j = 0; j < 16; j += 2) {
    u32 p = (u32)f2bf(tile[c4 + j][r]) | ((u32)f2bf(tile[c4 + j + 1][r]) << 16);
    *(u32*)&T[(size_t)(n0 + r) * DD + k0 + c4 + j] = p;
  }
}

// ---------------------------------------------------------------------------
// bf16 MFMA GEMM: C(MxN) = A(MxK bf16) @ BT(NxK bf16)^T + bias (+Res fp32)
// Round-10: BM=256 x BN=128, 8 waves (512 thr), 48 KB LDS dbuf -> 3
// blocks/CU = 24 waves/CU (was 16): more TLP to cover the 2-phase barrier
// drain, and B-panel traffic x0.75. Per-wave inner loop unchanged (wave
// (wm,wn) = (w&3, w>>2) owns a 64x64 sub-tile). launch_bounds(512,4) =
// 128-VGPR budget (NEVER below the 64-reg acc live set - round-6 lesson).
// + bijective XCD swizzle + ASHARE decode order (round 8).
template <bool OUT_BF16, bool ADD_RES, bool ROW_BIAS, bool QK, bool ASHARE>
__global__ __launch_bounds__(512, 4) void mfma_gemm_kernel(
    const u16* __restrict__ A, const u16* __restrict__ BT,
    const float* __restrict__ bias, const float* __restrict__ bias2,
    const float* __restrict__ Res,
    float* __restrict__ Cf, u16* __restrict__ Cb, u16* __restrict__ Cb2,
    int M, int N, int K) {
  __shared__ u16 Als[2][256 * 32];
  __shared__ u16 Bls[2][128 * 32];
  const int t  = threadIdx.x;

  // bijective XCD-aware remap of the flattened block id (m204 formula)
  const int gx = gridDim.x, gy = gridDim.y;
  const int nwg = gx * gy;
  int id = blockIdx.x + blockIdx.y * gx;
  {
    const int qq = nwg >> 3, rr = nwg & 7;
    const int xcd = id & 7, pos = id >> 3;
    id = (xcd < rr) ? (xcd * (qq + 1) + pos)
                    : (rr * (qq + 1) + (xcd - rr) * qq + pos);
  }
  int bm, bn;
  if (ASHARE) { bm = id / gy; bn = id % gy; }   // n-fastest: ids share A-panel
  else        { bm = id % gx; bn = id / gx; }   // m-fastest: ids share B-panel
  const int m0 = bm * 256;
  const int n0 = bn * 128;

  const int lane = t & 63;
  const int w  = t >> 6;          // 0..7
  const int wm = w & 3, wn = w >> 2;
  const int q  = lane >> 4;
  const int lr = lane & 15;

  // staging lane constants (BK=32 swizzle, see round-4 derivation)
  const int srow = lane >> 2;                       // 0..15
  const int schk = (lane & 3) ^ ((lane >> 3) & 3);  // pre-swizzled source chunk
  const u16* gA = A  + (size_t)(m0 + w * 32 + srow) * K + schk * 8;
  const u16* gB = BT + (size_t)(n0 + w * 16 + srow) * K + schk * 8;

  // read-side effective chunk (lane-constant)
  const int ceff = q ^ ((lr >> 1) & 3);

  // QK routing (block-uniform)
  const float* biasp = bias;
  u16* Cbp = Cb;
  int n0c = n0;
  if (QK && n0 >= DD) { biasp = bias2; Cbp = Cb2; n0c = n0 - DD; }

  ffrag acc[4][4];
  #pragma unroll
  for (int i = 0; i < 4; ++i)
    #pragma unroll
    for (int j = 0; j < 4; ++j) {
      acc[i][j].x = 0.f; acc[i][j].y = 0.f; acc[i][j].z = 0.f; acc[i][j].w = 0.f;
    }

  // wave w stages A rows w*32..+31 (2 insts) and B rows w*16..+15 (1 inst)
  auto STAGE = [&](int buf, int k0) {
    #pragma unroll
    for (int i = 0; i < 2; ++i)
      gl2lds16(gA + (size_t)(i * 16) * K + k0, &Als[buf][(w * 32 + i * 16) * 32]);
    gl2lds16(gB + k0, &Bls[buf][(w * 16) * 32]);
  };

  STAGE(0, 0);
  __syncthreads();

  const int NK = K >> 5;   // K/32
  for (int kt = 0; kt < NK; ++kt) {
    const int cur = kt & 1;
    if (kt + 1 < NK) STAGE(cur ^ 1, (kt + 1) << 5);

    bfrag af[4], bfv[4];
    #pragma unroll
    for (int mi = 0; mi < 4; ++mi)
      af[mi] = *(const bfrag*)&Als[cur][((wm * 4 + mi) * 64 + lr * 4 + ceff) * 8];
    #pragma unroll
    for (int ni = 0; ni < 4; ++ni)
      bfv[ni] = *(const bfrag*)&Bls[cur][((wn * 4 + ni) * 64 + lr * 4 + ceff) * 8];
    #pragma unroll
    for (int mi = 0; mi < 4; ++mi)
      #pragma unroll
      for (int ni = 0; ni < 4; ++ni)
        acc[mi][ni] = __builtin_amdgcn_mfma_f32_16x16x32_bf16(
            af[mi], bfv[ni], acc[mi][ni], 0, 0, 0);

    __syncthreads();   // prefetch of buf^1 landed; reads of buf done
  }

  float bcol[4];
  if (!ROW_BIAS) {
    #pragma unroll
    for (int ni = 0; ni < 4; ++ni)
      bcol[ni] = biasp[n0c + wn * 64 + ni * 16 + lr];
  }

  #pragma unroll
  for (int mi = 0; mi < 4; ++mi) {
    #pragma unroll
    for (int ni = 0; ni < 4; ++ni) {
      int gcol = n0c + wn * 64 + ni * 16 + lr;
      #pragma unroll
      for (int r = 0; r < 4; ++r) {
        int grow = m0 + wm * 64 + mi * 16 + q * 4 + r;
        size_t off = (size_t)grow * N + gcol;
        float v = acc[mi][ni][r];
        v += ROW_BIAS ? bias[grow] : bcol[ni];
        if (ADD_RES) v += Res[off];
        if (OUT_BF16) Cbp[off] = f2bf(v);
        else          Cf[off] = v;
      }
    }
  }
}

// ---------------------------------------------------------------------------
// Kernel 3a: per-(batch, 32-row-group) scores max/argmax (exact).
__global__ __launch_bounds__(256) void tome_scores_kernel(
    const float* __restrict__ metric, float* __restrict__ node_max,
    int* __restrict__ node_idx) {
  __shared__ float Bs[128][68];
  const int blk = blockIdx.x;
  const int b = blk >> 3, g = blk & 7;
  const int t = threadIdx.x;
  const int r = t >> 3, cc = t & 7;
  const int arow = g * 32 + r;
  const float* Mb = metric + (size_t)b * TT * 64;

  float areg[64];
  float na = 0.f;
  #pragma unroll
  for (int d4 = 0; d4 < 16; ++d4) {
    float4 v = *(const float4*)&Mb[(size_t)(2 * arow) * 64 + d4 * 4];
    areg[4 * d4 + 0] = v.x; areg[4 * d4 + 1] = v.y;
    areg[4 * d4 + 2] = v.z; areg[4 * d4 + 3] = v.w;
    na += v.x * v.x; na += v.y * v.y; na += v.z * v.z; na += v.w * v.w;
  }
  float ia = 1.f / (sqrtf(na) + 1e-6f);
  #pragma unroll
  for (int d = 0; d < 64; ++d) areg[d] *= ia;

  float best = -INFINITY; int besti = 0;
  for (int p = 0; p < 2; ++p) {
    __syncthreads();            // prior pass reads done
    if (t < 128) {              // stage cols p*128 .. +127, normalized
      int c = p * 128 + t;
      const float* src = &Mb[(size_t)(2 * c + 1) * 64];
      float nb = 0.f;
      #pragma unroll
      for (int d4 = 0; d4 < 16; ++d4) {
        float4 v = *(const float4*)&src[d4 * 4];
        *(float4*)&Bs[t][d4 * 4] = v;
        nb += v.x * v.x; nb += v.y * v.y; nb += v.z * v.z; nb += v.w * v.w;
      }
      float ib = 1.f / (sqrtf(nb) + 1e-6f);
      #pragma unroll
      for (int d4 = 0; d4 < 16; ++d4) {
        float4 v = *(float4*)&Bs[t][d4 * 4];
        v.x *= ib; v.y *= ib; v.z *= ib; v.w *= ib;
        *(float4*)&Bs[t][d4 * 4] = v;
      }
    }
    __syncthreads();
    for (int j = 0; j < 16; ++j) {
      int cl = cc + 8 * j;
      float s = 0.f;
      #pragma unroll
      for (int d4 = 0; d4 < 16; ++d4) {
        float4 bv = *(const float4*)&Bs[cl][d4 * 4];
        s += areg[4 * d4 + 0] * bv.x; s += areg[4 * d4 + 1] * bv.y;
        s += areg[4 * d4 + 2] * bv.z; s += areg[4 * d4 + 3] * bv.w;
      }
      int c = p * 128 + cl;
      if (s > best) { best = s; besti = c; }
    }
  }
  #pragma unroll
  for (int off = 1; off < 8; off <<= 1) {
    float bm = __shfl_xor(best, off);
    int   bi = __shfl_xor(besti, off);
    if (bm > best || (bm == best && bi < besti)) { best = bm; besti = bi; }
  }
  if (cc == 0) {
    node_max[b * TSRC + arow] = best;
    node_idx[b * TSRC + arow] = besti;
  }
}

// ---------------------------------------------------------------------------
// Kernel 3b: per-batch ranking + top-R selection (exact).
__global__ __launch_bounds__(256) void tome_rank_kernel(
    const float* __restrict__ node_max, const int* __restrict__ node_idx,
    int* __restrict__ order_g, int* __restrict__ dst_g) {
  __shared__ float km[TSRC];
  __shared__ int ord[TSRC];
  int b = blockIdx.x, i = threadIdx.x;
  float best = (i == 0) ? -INFINITY : node_max[b * TSRC + i];
  km[i] = best;
  __syncthreads();
  float ki = km[i];
  int r = 0;
  for (int j = 0; j < TSRC; ++j) {
    float kj = km[j];
    if (kj > ki || (kj == ki && j < i)) ++r;
  }
  ord[r] = i;
  __syncthreads();
  order_g[b * TSRC + i] = ord[i];
  if (i < RR) dst_g[b * RR + i] = node_idx[b * TSRC + ord[i]];
}

// ---------------------------------------------------------------------------
// Kernel 4: merge X -> Xm (fp32 residual) + Xm_bf (bf16 GEMM operand).
__global__ __launch_bounds__(256) void merge_kernel(
    const float* __restrict__ X, const int* __restrict__ order,
    const int* __restrict__ dsti, float* __restrict__ Xm,
    u16* __restrict__ Xmb) {
  int row = blockIdx.x;
  int b = row / TM, t2 = row % TM;
  int c = threadIdx.x;
  const float* Xb = X + (size_t)b * TT * DD;
  float out[3];
  if (t2 < UNM) {
    int tok = 2 * order[b * TSRC + RR + t2];
    #pragma unroll
    for (int l = 0; l < 3; ++l) out[l] = Xb[(size_t)tok * DD + c + 256 * l];
  } else {
    int j = t2 - UNM;
    float cnt = 1.f;
    #pragma unroll
    for (int l = 0; l < 3; ++l) out[l] = Xb[(size_t)(2 * j + 1) * DD + c + 256 * l];
    for (int m = 0; m < RR; ++m) {
      if (dsti[b * RR + m] == j) {
        int tok = 2 * order[b * TSRC + m];
        #pragma unroll
        for (int l = 0; l < 3; ++l) out[l] += Xb[(size_t)tok * DD + c + 256 * l];
        cnt += 1.f;
      }
    }
    float inv = 1.f / cnt;
    #pragma unroll
    for (int l = 0; l < 3; ++l) out[l] *= inv;
  }
  #pragma unroll
  for (int l = 0; l < 3; ++l) {
    Xm[(size_t)row * DD + c + 256 * l]  = out[l];
    Xmb[(size_t)row * DD + c + 256 * l] = f2bf(out[l]);
  }
}

// ---------------------------------------------------------------------------
// Kernel 5: MFMA flash attention, P never leaves registers (round 6).
// Round-10:
//  (a) dispatch remap: qt fastest within each XCD chunk (bijective,
//      3072 = 8 x 48 x 8) so a (b,h)'s 8 q-tiles run within a 64-id
//      window on ONE XCD -> K/VT stay L2-resident between q-tiles
//      (round-9 FETCH was 125 MB vs 74 ideal: later q-tiles re-fetched).
//  (b) VALU diet: v_cvt_pk_bf16_f32 for P packing (1 instr vs ~5, same
//      RNE rounding); max3-fusable fmax triples for the row max.
#define NQT 8
__global__ __launch_bounds__(256, 4) void attn_kernel(
    const u16* __restrict__ Q, const u16* __restrict__ K,
    const u16* __restrict__ VT, u16* __restrict__ ctx) {
  __shared__ u16 Kls[2][64][64];   // [buf][token][dim], chunk-swizzled
  __shared__ u16 Vls[2][64][64];   // [buf][dim][token], chunk+rowhalf-swizzled

  int blk = blockIdx.x;
  // qt-fastest XCD-local decode: native XCD = blk&7 (round-robin assumed;
  // performance-only). pos>>3 selects the (b,h) within the XCD's 48.
  int pos = blk >> 3, xcd = blk & 7;
  int qt = pos & 7;
  int bh = xcd * 48 + (pos >> 3);
  int h = bh % HH, b = bh / HH;
  const int t = threadIdx.x;
  const int lane = t & 63, w = t >> 6;
  const int lr = lane & 15, quad = lane >> 4;
  const int q0 = qt * 64;
  const size_t base = (size_t)b * TM * DD + (size_t)h * DHH;

  // Preload Q B-fragments: col n = lr -> q-row q0+16w+lr
  bfrag qf[2];
  {
    const u16* qp = Q + base + (size_t)(q0 + 16 * w + lr) * DD + quad * 8;
    qf[0] = *(const bfrag*)(qp);
    qf[1] = *(const bfrag*)(qp + 32);
  }

  // staging lane constants (see round-2 comment)
  const int srow = lane >> 3;
  const int schk = (lane & 7) ^ srow;
  const u16* Kg = K + base + (size_t)schk * 8;
  const u16* Vg0 = VT + (size_t)(h * DHH + w * 16 + srow) * MROW + (size_t)b * TM;
  const u16* Vg1 = Vg0 + (size_t)8 * MROW;

  // fragment-read chunk indices (swizzle involution on the read side)
  const int cA = (quad)     ^ (lr & 7);
  const int cB = (quad + 4) ^ (lr & 7);
  // PV b64 read offsets: logical chunk for token m*16+quad*4 is 2m+(quad>>1);
  // physical = logical ^ (lr&7) ^ hx; within-chunk byte offset (quad&1)*4.
  const int vq = quad >> 1, vh = (quad & 1) * 4, lx = lr & 7;
  const int hx = (lr >> 3) << 2;

  float m_i = -INFINITY, l_i = 0.f;   // running max in SCALED domain
  ffrag o[4];
  #pragma unroll
  for (int ni = 0; ni < 4; ++ni) {
    o[ni].x = 0.f; o[ni].y = 0.f; o[ni].z = 0.f; o[ni].w = 0.f;
  }

  auto STAGE = [&](int cur, int kt) {
    const int k0s = kt * 64;
    int t0 = k0s + w * 16 + srow;
    int t1 = t0 + 8;
    t0 = (t0 < TM) ? t0 : (TM - 1);
    t1 = (t1 < TM) ? t1 : (TM - 1);
    gl2lds16(Kg + (size_t)t0 * DD, &Kls[cur][w * 16][0]);
    gl2lds16(Kg + (size_t)t1 * DD, &Kls[cur][w * 16 + 8][0]);
    // V rows w*16..+7: rowhalf bit 0 -> source chunk schk
    int tb = k0s + schk * 8;
    tb = (tb <= TM - 8) ? tb : (TM - 8);
    gl2lds16(Vg0 + tb, &Vls[cur][w * 16][0]);
    // V rows w*16+8..+15: rowhalf bit 1 -> source chunk schk^4
    int tb2 = k0s + (schk ^ 4) * 8;
    tb2 = (tb2 <= TM - 8) ? tb2 : (TM - 8);
    gl2lds16(Vg1 + tb2, &Vls[cur][w * 16 + 8][0]);
  };

  STAGE(0, 0);
  __syncthreads();

  const float L2E = 1.4426950408889634f;
  const float C1  = 0.125f * 1.4426950408889634f;

  #pragma unroll
  for (int kt = 0; kt < NQT; ++kt) {
    const int cur = kt & 1;

    // issue next tile's staging first: latency hides under this tile's
    // compute; barrier at iteration end drains it.
    if (kt + 1 < NQT) STAGE(cur ^ 1, kt + 1);

    // S^T tile from LDS: s4[mi] covers tokens kt*64+mi*16+quad*4+r, row lr
    ffrag s4[4];
    __builtin_amdgcn_s_setprio(1);
    #pragma unroll
    for (int mi = 0; mi < 4; ++mi) {
      bfrag ka0 = *(const bfrag*)&Kls[cur][mi * 16 + lr][cA * 8];
      bfrag ka1 = *(const bfrag*)&Kls[cur][mi * 16 + lr][cB * 8];
      ffrag z; z.x = 0.f; z.y = 0.f; z.z = 0.f; z.w = 0.f;
      z = __builtin_amdgcn_mfma_f32_16x16x32_bf16(ka0, qf[0], z, 0, 0, 0);
      s4[mi] = __builtin_amdgcn_mfma_f32_16x16x32_bf16(ka1, qf[1], z, 0, 0, 0);
    }
    __builtin_amdgcn_s_setprio(0);

    // mask only the last tile (tokens 448..511 vs TM=504)
    if (kt == NQT - 1) {
      #pragma unroll
      for (int mi = 0; mi < 4; ++mi)
        #pragma unroll
        for (int r = 0; r < 4; ++r) {
          int rel = mi * 16 + quad * 4 + r;
          if (mi == 3)   // only mi==3 can overflow (rel>=56)
            s4[mi][r] = (448 + rel < TM) ? s4[mi][r] : -INFINITY;
        }
    }

    // raw-domain max via max3 triples (x0.125 is exact pow-2 scaling)
    float ma = max3f(s4[0][0], s4[0][1], s4[0][2]);
    float mb = max3f(s4[0][3], s4[1][0], s4[1][1]);
    float mc = max3f(s4[1][2], s4[1][3], s4[2][0]);
    float md = max3f(s4[2][1], s4[2][2], s4[2][3]);
    float me = max3f(s4[3][0], s4[3][1], s4[3][2]);
    float rmax = max3f(fmaxf(ma, mb), fmaxf(mc, md), fmaxf(me, s4[3][3]));
    rmax = fmaxf(rmax, __shfl_xor(rmax, 16));
    rmax = fmaxf(rmax, __shfl_xor(rmax, 32));
    float pmax = rmax * 0.125f;

    // T13 defer-max: rescale only if some q-row's max grew by >8.
    if (!__all(pmax <= m_i + 8.f)) {
      float nm = fmaxf(m_i, pmax);
      float alpha = __builtin_amdgcn_exp2f((m_i - nm) * L2E);  // first: 0
      float al[4];
      #pragma unroll
      for (int r = 0; r < 4; ++r) al[r] = __shfl(alpha, quad * 4 + r);
      #pragma unroll
      for (int ni = 0; ni < 4; ++ni)
        #pragma unroll
        for (int r = 0; r < 4; ++r) o[ni][r] *= al[r];
      l_i *= alpha;
      m_i = nm;
    }
    float nml2 = m_i * L2E;

    // p = exp2(s*0.125*log2e - m*log2e) == exp(s*0.125 - m), bounded e^8
    float p[16];
    float pa0 = 0.f, pa1 = 0.f, pa2 = 0.f, pa3 = 0.f;
    #pragma unroll
    for (int mi = 0; mi < 4; ++mi)
      #pragma unroll
      for (int r = 0; r < 4; ++r) {
        float e = __builtin_amdgcn_exp2f(__builtin_fmaf(s4[mi][r], C1, -nml2));
        p[mi * 4 + r] = e;
        if (r == 0) pa0 += e; else if (r == 1) pa1 += e;
        else if (r == 2) pa2 += e; else pa3 += e;
      }
    float psum = (pa0 + pa1) + (pa2 + pa3);
    psum += __shfl_xor(psum, 16);
    psum += __shfl_xor(psum, 32);
    l_i += psum;

    // pack P in-register via HW cvt_pk (RNE): pk[2mi] = tokens
    // mi*16+quad*4+{0,1}, pk[2mi+1] = +{2,3}
    u32 pk[8];
    #pragma unroll
    for (int mi = 0; mi < 4; ++mi) {
      pk[2 * mi]     = cvtpk2bf(p[mi * 4 + 0], p[mi * 4 + 1]);
      pk[2 * mi + 1] = cvtpk2bf(p[mi * 4 + 2], p[mi * 4 + 3]);
    }

    // PV: A = pk (registers, relabeled k-slots), B = V tokens from LDS
    __builtin_amdgcn_s_setprio(1);
    #pragma unroll
    for (int mh = 0; mh < 2; ++mh) {
      // A-frag: shorts 0..3 = tokens (2mh)*16+quad*4..+3,
      //         shorts 4..7 = tokens (2mh+1)*16+quad*4..+3
      union { u32 u[4]; bfrag f; } pa;
      pa.u[0] = pk[4 * mh + 0]; pa.u[1] = pk[4 * mh + 1];
      pa.u[2] = pk[4 * mh + 2]; pa.u[3] = pk[4 * mh + 3];
      const int c0 = ((4 * mh + vq) ^ lx ^ hx) * 8 + vh;       // m = 2mh
      const int c1 = ((4 * mh + 2 + vq) ^ lx ^ hx) * 8 + vh;   // m = 2mh+1
      #pragma unroll
      for (int ni = 0; ni < 4; ++ni) {
        const u16* vp = &Vls[cur][ni * 16 + lr][0];
        u32x2 v0 = *(const u32x2*)(vp + c0);
        u32x2 v1 = *(const u32x2*)(vp + c1);
        union { u32 u[4]; bfrag f; } vb;
        vb.u[0] = v0.x; vb.u[1] = v0.y; vb.u[2] = v1.x; vb.u[3] = v1.y;
        o[ni] = __builtin_amdgcn_mfma_f32_16x16x32_bf16(pa.f, vb.f, o[ni], 0, 0, 0);
      }
    }
    __builtin_amdgcn_s_setprio(0);

    __syncthreads();   // staged tile kt+1 complete; buf reuse safe
  }

  // epilogue: O /= l, store bf16
  float invl[4];
  #pragma unroll
  for (int r = 0; r < 4; ++r) {
    float lv = __shfl(l_i, quad * 4 + r);
    invl[r] = 1.f / lv;
  }
  #pragma unroll
  for (int r = 0; r < 4; ++r) {
    int row = q0 + 16 * w + quad * 4 + r;
    if (row < TM) {
      size_t g = base + (size_t)row * DD + lr;
      #pragma unroll
      for (int ni = 0; ni < 4; ++ni)
        ctx[g + ni * 16] = f2bf(o[ni][r] * invl[r]);
    }
  }
}

// ---------------------------------------------------------------------------
// Kernel 7: in-place LayerNorm on d_out rows (768 wide).
__global__ __launch_bounds__(256) void ln_kernel(
    float* __restrict__ Y, const float* __restrict__ g,
    const float* __restrict__ beta) {
  __shared__ float red[4];
  int row = blockIdx.x, t = threadIdx.x;
  size_t baseo = (size_t)row * DD;
  float x[3];
  #pragma unroll
  for (int l = 0; l < 3; ++l) x[l] = Y[baseo + t + 256 * l];
  float s = x[0] + x[1] + x[2];
  #pragma unroll
  for (int off = 32; off > 0; off >>= 1) s += __shfl_down(s, off, 64);
  if ((t & 63) == 0) red[t >> 6] = s;
  __syncthreads();
  float mu = (red[0] + red[1] + red[2] + red[3]) * (1.f / 768.f);
  __syncthreads();
  float d0 = x[0] - mu, d1 = x[1] - mu, d2 = x[2] - mu;
  float sq = d0 * d0 + d1 * d1 + d2 * d2;
  #pragma unroll
  for (int off = 32; off > 0; off >>= 1) sq += __shfl_down(sq, off, 64);
  if ((t & 63) == 0) red[t >> 6] = sq;
  __syncthreads();
  float var = (red[0] + red[1] + red[2] + red[3]) * (1.f / 768.f);
  float inv = rsqrtf(var + 1e-12f);
  #pragma unroll
  for (int l = 0; l < 3; ++l) {
    int c = t + 256 * l;
    Y[baseo + c] = (x[l] - mu) * inv * g[c] + beta[c];
  }
}

// ---------------------------------------------------------------------------
extern "C" void kernel_launch(void* const* d_in, const int* in_sizes, int n_in,
                              void* d_out, int out_size, void* d_ws, size_t ws_size,
                              hipStream_t stream) {
  const float* X    = (const float*)d_in[0];
  const float* Wq   = (const float*)d_in[1];
  const float* bq   = (const float*)d_in[2];
  const float* Wk   = (const float*)d_in[3];
  const float* bk   = (const float*)d_in[4];
  const float* Wv   = (const float*)d_in[5];
  const float* bv   = (const float*)d_in[6];
  const float* Wo   = (const float*)d_in[7];
  const float* bo   = (const float*)d_in[8];
  const float* ln_g = (const float*)d_in[9];
  const float* ln_b = (const float*)d_in[10];
  float* out = (float*)d_out;

  const size_t metric_n = (size_t)16384 * 64;
  const size_t wkr_n    = (size_t)768 * 64 + 64;
  const size_t idx_n    = (size_t)BNUM * TSRC + BNUM * RR;
  const size_t nm_n     = (size_t)2 * BNUM * TSRC;   // node_max f32 + node_idx int
  const size_t buf_n    = (size_t)MROW * DD;
  const size_t w_n      = (size_t)DD * DD;
  const size_t f32_elems = metric_n + wkr_n + idx_n + nm_n + buf_n;
  const size_t u16_elems = 4 * buf_n + 4 * w_n;
  const size_t needed = f32_elems * 4 + u16_elems * 2;
  if (ws_size < needed) return;

  float* ws = (float*)d_ws;
  float* metric   = ws;
  float* Wkr      = metric + metric_n;
  float* bkr      = Wkr + (size_t)768 * 64;
  int*   order_g  = (int*)(bkr + 64);
  int*   dst_g    = order_g + BNUM * TSRC;
  float* node_max = (float*)(dst_g + BNUM * RR);
  int*   node_idx = (int*)(node_max + BNUM * TSRC);
  float* Xm       = (float*)(node_idx + BNUM * TSRC);
  u16*   Xmb      = (u16*)(Xm + buf_n);
  u16*   Qmb      = Xmb + buf_n;
  u16*   Kmb      = Qmb + buf_n;
  u16*   VTb      = Kmb + buf_n;     // V^T: [768][MROW]
  u16*   WqT      = VTb + buf_n;
  u16*   WkT      = WqT + w_n;       // contiguous after WqT -> [1536][768]
  u16*   WvT      = WkT + w_n;
  u16*   WoT      = WvT + w_n;
  u16*   ctxb     = Qmb;   // alias: safe, see attn_kernel note

  wkr_kernel<<<(768 * 64) / 256, 256, 0, stream>>>(Wk, bk, Wkr, bkr);
  wconv_kernel<<<dim3(12, 12, 4), 256, 0, stream>>>(
      Wq, Wk, Wv, Wo, WqT, WkT, WvT, WoT);
  gemm_f32_kernel<<<dim3(16384 / 64, 1), 256, 0, stream>>>(
      X, Wkr, bkr, metric, 16384, 64, 768);
  tome_scores_kernel<<<BNUM * 8, 256, 0, stream>>>(metric, node_max, node_idx);
  tome_rank_kernel<<<BNUM, 256, 0, stream>>>(node_max, node_idx, order_g, dst_g);
  merge_kernel<<<MROW, 256, 0, stream>>>(X, order_g, dst_g, Xm, Xmb);
  // Q and K fused: B = [WqT|WkT]; ASHARE=1 (A=Xmb is the big re-read operand)
  mfma_gemm_kernel<true, false, false, true, true>
      <<<dim3(MROW / 256, 2 * DD / 128), 512, 0, stream>>>(
      Xmb, WqT, bq, bk, nullptr, nullptr, Qmb, Kmb, MROW, DD, DD);
  // V^T: A = WvT (tiny), B = Xmb (big) -> m-fastest (ASHARE=0)
  mfma_gemm_kernel<true, false, true, false, false>
      <<<dim3(DD / 256, MROW / 128), 512, 0, stream>>>(
      WvT, Xmb, bv, nullptr, nullptr, nullptr, VTb, nullptr, DD, MROW, DD);
  attn_kernel<<<BNUM * HH * NQT, 256, 0, stream>>>(Qmb, Kmb, VTb, ctxb);
  // Wo: A = ctx (big re-read) -> ASHARE=1
  mfma_gemm_kernel<false, true, false, false, true>
      <<<dim3(MROW / 256, DD / 128), 512, 0, stream>>>(
      ctxb, WoT, bo, nullptr, Xm, out, nullptr, nullptr, MROW, DD, DD);
  ln_kernel<<<MROW, 256, 0, stream>>>(out, ln_g, ln_b);
}